// Round 10
// baseline (216.189 us; speedup 1.0000x reference)
//
#include <hip/hip_runtime.h>
#include <hip/hip_bf16.h>
#include <hip/hip_cooperative_groups.h>
#include <math.h>

namespace cg = cooperative_groups;

// ---------------------------------------------------------------------------
// BarrierNet forward, round 10: ONE cooperative mega-kernel.
// Grid 256 x 512thr, 144 KiB LDS -> exactly 1 block/CU (co-resident), phases
//   {weight-transpose + layer1 + b3cat} -> L2 -> L3 -> L4 -> head
// separated by cg::this_grid().sync().  GEMM core = R5's verified best
// (78.8us): 8 waves, wave-tile 64x64, triple-buffered LDS, ONE barrier per
// K-tile, stage-ahead-2, counted vmcnt(6), setprio, XOR-swizzled LDS via
// pre-swizzled global source, XCD-bijective sid swizzle.
// R6/R8: finer phases hurt. R7: A-from-global hurts (64 lines/instr).
// R9: fat waves hurt (1 wave/SIMD). This round removes LAUNCH overhead only.
// Aliasing: x3 reuses xb1, x4 reuses x2b -- WAR-safe across grid syncs.
// ---------------------------------------------------------------------------

typedef __attribute__((ext_vector_type(4))) float f32x4;
typedef __attribute__((ext_vector_type(8))) short bf16x8;

static __device__ __forceinline__ unsigned short f2bf(float f) {
    unsigned int u = __float_as_uint(f);
    unsigned int r = (u + 0x7fffu + ((u >> 16) & 1u)) >> 16;
    return (unsigned short)r;
}
static __device__ __forceinline__ float bf2f(unsigned short h) {
    return __uint_as_float(((unsigned int)h) << 16);
}

#define TBM 128
#define TBN 256
#define TBK 64

#define GLL(gp, lp) __builtin_amdgcn_global_load_lds( \
    (const __attribute__((address_space(1))) void*)(gp), \
    (__attribute__((address_space(3))) void*)(lp), 16, 0, 0)

#define VMC(N)  asm volatile("s_waitcnt vmcnt(" #N ")" ::: "memory")
#define BAR()   __builtin_amdgcn_s_barrier()
#define SB0()   __builtin_amdgcn_sched_barrier(0)

// R5 gemm_core verbatim, but shared arrays passed in.
// C[., c0+j] = relu(A[m0+i,:] . Bt[n0b+j,:] + bias[n0b+j]); nt = K/64 >= 3.
__device__ __forceinline__ void gemm_core(
    const unsigned short* __restrict__ A, int lda,
    const unsigned short* __restrict__ Bt, int ldb,
    const float* __restrict__ bias,
    unsigned short* __restrict__ C, int ldc,
    int K, int m0, int n0b, int c0,
    short* sAb, short* sBb)            // [3][TBM*TBK], [3][TBN*TBK]
{
    const int tid  = threadIdx.x;
    const int w    = tid >> 6;         // wave 0..7
    const int lane = tid & 63;

    const int srow = lane >> 3;
    const int skq  = (lane & 7) ^ ((lane >> 3) & 7);
    const unsigned short* aP0 =
        A + (size_t)(m0 + 16 * w + srow) * lda + skq * 8;
    const unsigned short* aP1 = aP0 + 8 * lda;
    const unsigned short* bP0 =
        Bt + (size_t)(n0b + 32 * w + srow) * ldb + skq * 8;
    const unsigned short* bP1 = bP0 + 8 * ldb;
    const unsigned short* bP2 = bP0 + 16 * ldb;
    const unsigned short* bP3 = bP0 + 24 * ldb;

    const int wrow = (w >> 2) * 64;
    const int wcol = (w & 3) * 64;
    const int fr = lane & 15;
    const int fq = lane >> 4;
    const int swz0 = ((fq)     ^ (fr & 7)) * 8;
    const int swz1 = ((4 + fq) ^ (fr & 7)) * 8;

    f32x4 acc[4][4] = {};
    const int nt = K / TBK;

    auto STAGE = [&](int kt, int b) {
        const size_t ko = (size_t)kt * TBK;
        short* la = sAb + b * (TBM * TBK);
        short* lb = sBb + b * (TBN * TBK);
        GLL(aP0 + ko, la + (2 * w)     * 512);
        GLL(aP1 + ko, la + (2 * w + 1) * 512);
        GLL(bP0 + ko, lb + (4 * w)     * 512);
        GLL(bP1 + ko, lb + (4 * w + 1) * 512);
        GLL(bP2 + ko, lb + (4 * w + 2) * 512);
        GLL(bP3 + ko, lb + (4 * w + 3) * 512);
    };

    STAGE(0, 0);
    STAGE(1, 1);
    VMC(6);
    BAR();
    SB0();

    int cur = 0, stg = 2;
    for (int t = 0; t < nt; ++t) {
        const short* sAp = sAb + cur * (TBM * TBK);
        const short* sBp = sBb + cur * (TBN * TBK);

        bf16x8 af[2][4], bf[2][4];
        #pragma unroll
        for (int m = 0; m < 4; ++m) {
            const int r = (wrow + m * 16 + fr) * 64;
            af[0][m] = *reinterpret_cast<const bf16x8*>(&sAp[r + swz0]);
            af[1][m] = *reinterpret_cast<const bf16x8*>(&sAp[r + swz1]);
        }
        #pragma unroll
        for (int n = 0; n < 4; ++n) {
            const int r = (wcol + n * 16 + fr) * 64;
            bf[0][n] = *reinterpret_cast<const bf16x8*>(&sBp[r + swz0]);
            bf[1][n] = *reinterpret_cast<const bf16x8*>(&sBp[r + swz1]);
        }

        if (t + 2 < nt) STAGE(t + 2, stg);

        __builtin_amdgcn_s_setprio(1);
        #pragma unroll
        for (int kh = 0; kh < 2; ++kh)
            #pragma unroll
            for (int m = 0; m < 4; ++m)
                #pragma unroll
                for (int n = 0; n < 4; ++n)
                    acc[m][n] = __builtin_amdgcn_mfma_f32_16x16x32_bf16(
                        af[kh][m], bf[kh][n], acc[m][n], 0, 0, 0);
        __builtin_amdgcn_s_setprio(0);

        if (t + 1 < nt) {
            if (t + 2 < nt) { VMC(6); } else { VMC(0); }
            BAR();
            SB0();
        }
        cur = (cur == 2) ? 0 : cur + 1;
        stg = (stg == 2) ? 0 : stg + 1;
    }

    // C/D layout: col = lane&15, row = (lane>>4)*4 + reg  [m89/m91 verified]
    #pragma unroll
    for (int n = 0; n < 4; ++n) {
        const int cl = wcol + n * 16 + fr;
        const float bv = bias[n0b + cl];
        #pragma unroll
        for (int m = 0; m < 4; ++m) {
            const int rbase = m0 + wrow + m * 16 + fq * 4;
            #pragma unroll
            for (int r = 0; r < 4; ++r) {
                float v = fmaxf(acc[m][n][r] + bv, 0.0f);
                C[(size_t)(rbase + r) * ldc + c0 + cl] = f2bf(v);
            }
        }
    }
}

struct MegaParams {
    const float *x, *mean, *stdv, *mean_label, *std_label;
    const float *W1, *b1, *W2, *b2, *W31, *b31, *W32, *b32;
    const float *W41, *b41, *W42, *b42, *W51, *b51, *W52, *b52;
    unsigned short *xb1, *x2b, *W2t, *W3t, *W41t, *W42t;
    float *b3c;
    float *out;
};

__global__ __launch_bounds__(512, 2) void mega_kernel(MegaParams P)
{
    __shared__ __align__(16) short sA[3][TBM * TBK];   // 48 KiB
    __shared__ __align__(16) short sB[3][TBN * TBK];   // 96 KiB
    cg::grid_group grid = cg::this_grid();

    const int bid = blockIdx.x;       // 0..255
    const int tid = threadIdx.x;      // 0..511

    // ================= phase 0: weight prep + layer1 + b3cat ===============
    {
        // (a) transposes: 2 engines/block x 256 blocks = 512 engines,
        // 2560 tiles of 32x32, exactly 5 per engine (uniform trip count).
        const int eng  = bid * 2 + (tid >> 8);
        const int etid = tid & 255;
        float* tbuf = (float*)((char*)&sA[0][0] + (tid >> 8) * 4352);
        const int tx = etid & 31, ty = etid >> 5;     // 32 x 8
        #pragma unroll 1
        for (int T = eng; T < 2560; T += 512) {
            const float* src; unsigned short* dst; int N, ti;
            if (T < 1024)      { src = P.W2;  dst = P.W2t;            N = 1024; ti = T; }
            else if (T < 1536) { src = P.W31; dst = P.W3t;            N = 512;  ti = T - 1024; }
            else if (T < 2048) { src = P.W32; dst = P.W3t + 512*1024; N = 512;  ti = T - 1536; }
            else if (T < 2304) { src = P.W41; dst = P.W41t;           N = 512;  ti = T - 2048; }
            else               { src = P.W42; dst = P.W42t;           N = 512;  ti = T - 2304; }
            const int ntk = (T < 2048) ? 32 : 16;     // K/32
            const int Kd  = ntk * 32;
            const int k0 = (ti % ntk) * 32, n0 = (ti / ntk) * 32;
            #pragma unroll
            for (int i = 0; i < 32; i += 8)
                tbuf[(ty + i) * 33 + tx] = src[(size_t)(k0 + ty + i) * N + n0 + tx];
            __syncthreads();
            #pragma unroll
            for (int i = 0; i < 32; i += 8)
                dst[(size_t)(n0 + ty + i) * Kd + k0 + tx] = f2bf(tbuf[tx * 33 + ty + i]);
            __syncthreads();
        }

        // (b) layer1: rows bid*32 + (tid>>8)*16 .. +16, col4 = (tid&255)*4
        const int j4 = (tid & 255) * 4;
        const int r0 = bid * 32 + (tid >> 8) * 16;
        float4 wv[5];
        #pragma unroll
        for (int k = 0; k < 5; ++k)
            wv[k] = *reinterpret_cast<const float4*>(&P.W1[k * 1024 + j4]);
        const float4 bb = *reinterpret_cast<const float4*>(&P.b1[j4]);
        #pragma unroll 1
        for (int r = 0; r < 16; ++r) {
            const float* xr = &P.x[(size_t)(r0 + r) * 5];
            float4 acc = bb;
            #pragma unroll
            for (int k = 0; k < 5; ++k) {
                const float xv = xr[k];
                acc.x = fmaf(xv, wv[k].x, acc.x);
                acc.y = fmaf(xv, wv[k].y, acc.y);
                acc.z = fmaf(xv, wv[k].z, acc.z);
                acc.w = fmaf(xv, wv[k].w, acc.w);
            }
            ushort4 o;
            o.x = f2bf(fmaxf(acc.x, 0.f));
            o.y = f2bf(fmaxf(acc.y, 0.f));
            o.z = f2bf(fmaxf(acc.z, 0.f));
            o.w = f2bf(fmaxf(acc.w, 0.f));
            *reinterpret_cast<ushort4*>(&P.xb1[(size_t)(r0 + r) * 1024 + j4]) = o;
        }

        // (c) b3cat (block 0)
        if (bid == 0) {
            const int i = tid;
            P.b3c[i]       = (i < 512) ? P.b31[i] : P.b32[i - 512];
            P.b3c[i + 512] = ((i + 512) < 512) ? P.b31[i + 512] : P.b32[i];
        }
    }
    grid.sync();

    // sid: XCD-bijective swizzle (bid%8 = XCD id; 32 sids per XCD)
    const int sid = (bid & 7) * 32 + (bid >> 3);
    unsigned short* x3 = P.xb1;        // aliases, WAR-safe across grid syncs
    unsigned short* x4 = P.x2b;

    // ================= L2: x2b = relu(xb1 @ W2t^T + b2) ====================
    {
        const int n0 = (sid & 3) * TBN;
        const int m0 = (sid >> 2) * TBM;
        gemm_core(P.xb1, 1024, P.W2t, 1024, P.b2, P.x2b, 1024, 1024,
                  m0, n0, n0, &sA[0][0], &sB[0][0]);
    }
    grid.sync();

    // ================= L3: x3 = relu(x2b @ [W31|W32]t^T + b3c) =============
    {
        const int n0 = (sid & 3) * TBN;
        const int m0 = (sid >> 2) * TBM;
        gemm_core(P.x2b, 1024, P.W3t, 1024, P.b3c, x3, 1024, 1024,
                  m0, n0, n0, &sA[0][0], &sB[0][0]);
    }
    grid.sync();

    // ================= L4 grouped: x4 = relu(x3[g] @ W4g^T + b4g) ==========
    {
        const int xp  = sid & 3;
        const int g   = xp >> 1;
        const int n0b = (xp & 1) * TBN;
        const int m0  = (sid >> 2) * TBM;
        gemm_core(x3 + (g ? 512 : 0), 1024, g ? P.W42t : P.W41t, 512,
                  g ? P.b42 : P.b41, x4, 1024, 512,
                  m0, n0b, g * 512 + n0b, &sA[0][0], &sB[0][0]);
    }
    grid.sync();

    // ================= head: rows bid*32 .. +32, wave per row ==============
    {
        const int wave = tid >> 6;     // 0..7
        const int lane = tid & 63;
        const float4 q0 = *reinterpret_cast<const float4*>(P.W51 + lane * 16 + 0);
        const float4 q1 = *reinterpret_cast<const float4*>(P.W51 + lane * 16 + 4);
        const float4 q2 = *reinterpret_cast<const float4*>(P.W51 + lane * 16 + 8);
        const float4 q3 = *reinterpret_cast<const float4*>(P.W51 + lane * 16 + 12);
        const float4 s0 = *reinterpret_cast<const float4*>(P.W52 + lane * 16 + 0);
        const float4 s1 = *reinterpret_cast<const float4*>(P.W52 + lane * 16 + 4);
        const float4 s2 = *reinterpret_cast<const float4*>(P.W52 + lane * 16 + 8);
        const float4 s3 = *reinterpret_cast<const float4*>(P.W52 + lane * 16 + 12);

        #pragma unroll 1
        for (int it = 0; it < 4; ++it) {
            const int row = bid * 32 + it * 8 + wave;
            const unsigned short* p41 = x4 + (size_t)row * 1024;
            const bf16x8 v1 = *reinterpret_cast<const bf16x8*>(p41 + lane * 8);
            const bf16x8 v2 = *reinterpret_cast<const bf16x8*>(p41 + 512 + lane * 8);

            float a0, a1, a2, a3;
            {
                const float e0 = bf2f((unsigned short)v1[0]), e1 = bf2f((unsigned short)v1[1]),
                            e2 = bf2f((unsigned short)v1[2]), e3 = bf2f((unsigned short)v1[3]),
                            e4 = bf2f((unsigned short)v1[4]), e5 = bf2f((unsigned short)v1[5]),
                            e6 = bf2f((unsigned short)v1[6]), e7 = bf2f((unsigned short)v1[7]);
                a0 = e0*q0.x + e1*q0.z + e2*q1.x + e3*q1.z + e4*q2.x + e5*q2.z + e6*q3.x + e7*q3.z;
                a1 = e0*q0.y + e1*q0.w + e2*q1.y + e3*q1.w + e4*q2.y + e5*q2.w + e6*q3.y + e7*q3.w;
                const float f0 = bf2f((unsigned short)v2[0]), f1 = bf2f((unsigned short)v2[1]),
                            f2 = bf2f((unsigned short)v2[2]), f3 = bf2f((unsigned short)v2[3]),
                            f4 = bf2f((unsigned short)v2[4]), f5 = bf2f((unsigned short)v2[5]),
                            f6 = bf2f((unsigned short)v2[6]), f7 = bf2f((unsigned short)v2[7]);
                a2 = f0*s0.x + f1*s0.z + f2*s1.x + f3*s1.z + f4*s2.x + f5*s2.z + f6*s3.x + f7*s3.z;
                a3 = f0*s0.y + f1*s0.w + f2*s1.y + f3*s1.w + f4*s2.y + f5*s2.w + f6*s3.y + f7*s3.w;
            }
            #pragma unroll
            for (int off = 32; off >= 1; off >>= 1) {
                a0 += __shfl_down(a0, off);
                a1 += __shfl_down(a1, off);
                a2 += __shfl_down(a2, off);
                a3 += __shfl_down(a3, off);
            }

            if (lane == 0) {
                const float L1c = 3.0f, L2c = 3.0f, OBSY = 7.0f, Rc = 4.0f;
                const float t1 = P.x[row * 5 + 0] * P.stdv[0] + P.mean[0];
                const float w1 = P.x[row * 5 + 1] * P.stdv[1] + P.mean[1];
                const float t2 = P.x[row * 5 + 2] * P.stdv[2] + P.mean[2];
                const float w2 = P.x[row * 5 + 3] * P.stdv[3] + P.mean[3];
                const float s1v = sinf(t1), c1 = cosf(t1);
                const float s2v = sinf(t2), c2 = cosf(t2);
                const float px = L1c * c1 + L2c * c2;
                const float py = L1c * s1v + L2c * s2v - OBSY;
                const float vx = -L1c * s1v * w1 - L2c * s2v * w2;
                const float vy =  L1c * c1 * w1 + L2c * c2 * w2;
                const float barrier = px * px + py * py - Rc * Rc;
                const float b_dot = 2.0f * (px * vx + py * vy);
                const float Lf2b = 2.0f * (vx * vx + vy * vy)
                                 + 2.0f * px * (-L1c * c1 * w1 * w1 - L2c * c2 * w2 * w2)
                                 + 2.0f * py * (-L1c * s1v * w1 * w1 - L2c * s2v * w2 * w2);
                const float G1 = -(2.0f * px * (-L1c * s1v) + 2.0f * py * (L1c * c1));
                const float G2 = -(2.0f * px * (-L2c * s2v) + 2.0f * py * (L2c * c2));

                const float x51_0 = a0 + P.b51[0];
                const float x51_1 = a1 + P.b51[1];
                const float z0 = a2 + P.b52[0];
                const float z1 = a3 + P.b52[1];
                const float x52_0 = 4.0f / (1.0f + expf(-z0));
                const float x52_1 = 4.0f / (1.0f + expf(-z1));

                const float u0_0 = -x51_0;
                const float u0_1 = -x51_1;
                const float h = Lf2b + (x52_0 + x52_1) * b_dot + x52_0 * x52_1 * barrier;
                const float viol = G1 * u0_0 + G2 * u0_1 - h;
                const float lam = fmaxf(viol, 0.0f) / (G1 * G1 + G2 * G2 + 1e-12f);
                const float u_0 = u0_0 - lam * G1;
                const float u_1 = u0_1 - lam * G2;
                P.out[row * 2 + 0] = (u_0 - P.mean_label[0]) / P.std_label[0];
                P.out[row * 2 + 1] = (u_1 - P.mean_label[1]) / P.std_label[1];
            }
        }
    }
}

extern "C" void kernel_launch(void* const* d_in, const int* in_sizes, int n_in,
                              void* d_out, int out_size, void* d_ws, size_t ws_size,
                              hipStream_t stream) {
    char* ws = (char*)d_ws;
    const size_t MiB = 1024 * 1024;

    MegaParams P;
    P.x          = (const float*)d_in[0];
    P.mean       = (const float*)d_in[2];
    P.stdv       = (const float*)d_in[3];
    P.mean_label = (const float*)d_in[4];
    P.std_label  = (const float*)d_in[5];
    P.W1  = (const float*)d_in[6];   P.b1  = (const float*)d_in[7];
    P.W2  = (const float*)d_in[8];   P.b2  = (const float*)d_in[9];
    P.W31 = (const float*)d_in[10];  P.b31 = (const float*)d_in[11];
    P.W32 = (const float*)d_in[12];  P.b32 = (const float*)d_in[13];
    P.W41 = (const float*)d_in[14];  P.b41 = (const float*)d_in[15];
    P.W42 = (const float*)d_in[16];  P.b42 = (const float*)d_in[17];
    P.W51 = (const float*)d_in[18];  P.b51 = (const float*)d_in[19];
    P.W52 = (const float*)d_in[20];  P.b52 = (const float*)d_in[21];
    P.xb1  = (unsigned short*)(ws + 0);          // later x3
    P.x2b  = (unsigned short*)(ws + 16 * MiB);   // later x4
    P.W2t  = (unsigned short*)(ws + 32 * MiB);
    P.W3t  = (unsigned short*)(ws + 34 * MiB);
    P.W41t = (unsigned short*)(ws + 36 * MiB);
    P.W42t = (unsigned short*)(ws + 36 * MiB + 512 * 1024);
    P.b3c  = (float*)(ws + 37 * MiB);
    P.out  = (float*)d_out;

    void* kargs[] = { (void*)&P };
    hipLaunchCooperativeKernel(reinterpret_cast<void*>(mega_kernel),
                               dim3(256), dim3(512), kargs, 0, stream);
}

// Round 11
// 87.761 us; speedup vs baseline: 2.4634x; 2.4634x over previous
//
#include <hip/hip_runtime.h>
#include <hip/hip_bf16.h>
#include <math.h>

// ---------------------------------------------------------------------------
// BarrierNet forward, round 11 = R5 (best, 78.8us) restored, + two micro-opts:
//  (1) STAGE(t+2) issued BEFORE fragment ds_reads (earlier VMEM issue; T3
//      recipe ordering) -- pure issue reorder, sync structure unchanged.
//  (2) head kernel rows XCD-aligned to L4's swizzle (x4 rows [1024k,1024k+1024)
//      live in XCD k's L2; head block b reads rows (b&7)*1024 + (b>>3)*4).
// GEMM: BM=128 x BN=256 x BK=64, 8 waves, wave-tile 64x64, TRIPLE-buffered
// LDS (144 KiB), ONE barrier/K-tile, counted vmcnt(6), setprio, XOR-swizzled
// LDS via pre-swizzled global source, XCD-bijective block swizzle.
// Refuted structures: finer phases (R6/R8), A-from-global (R7), fat waves
// (R9), cooperative mega-kernel (R10: 650 GB/s, 8% MfmaUtil).
// ---------------------------------------------------------------------------

typedef __attribute__((ext_vector_type(4))) float f32x4;
typedef __attribute__((ext_vector_type(8))) short bf16x8;

static __device__ __forceinline__ unsigned short f2bf(float f) {
    unsigned int u = __float_as_uint(f);
    unsigned int r = (u + 0x7fffu + ((u >> 16) & 1u)) >> 16;
    return (unsigned short)r;
}
static __device__ __forceinline__ float bf2f(unsigned short h) {
    return __uint_as_float(((unsigned int)h) << 16);
}

#define TBM 128
#define TBN 256
#define TBK 64

#define GLL(gp, lp) __builtin_amdgcn_global_load_lds( \
    (const __attribute__((address_space(1))) void*)(gp), \
    (__attribute__((address_space(3))) void*)(lp), 16, 0, 0)

#define VMC(N)  asm volatile("s_waitcnt vmcnt(" #N ")" ::: "memory")
#define BAR()   __builtin_amdgcn_s_barrier()
#define SB0()   __builtin_amdgcn_sched_barrier(0)

// C[., c0+j] = relu(A[m0+i,:] . Bt[n0b+j,:] + bias[n0b+j])
// A: bf16 row-major lda; Bt: bf16 row-major ldb (N x K); nt = K/64 >= 3.
__device__ __forceinline__ void gemm_core(
    const unsigned short* __restrict__ A, int lda,
    const unsigned short* __restrict__ Bt, int ldb,
    const float* __restrict__ bias,
    unsigned short* __restrict__ C, int ldc,
    int K, int m0, int n0b, int c0)
{
    // A tile 16 KiB, B tile 32 KiB, x3 buffers = 144 KiB
    __shared__ __align__(16) short sA[3][TBM * TBK];
    __shared__ __align__(16) short sB[3][TBN * TBK];

    const int tid  = threadIdx.x;
    const int w    = tid >> 6;         // wave 0..7
    const int lane = tid & 63;

    // ---- staging addresses (pre-swizzled global source; verified R4/R5) ----
    // chunk = 1 KiB = 8 rows x 8 granules of 16B. lane l -> row base+(l>>3),
    // granule kq = (l&7) ^ ((l>>3)&7).
    const int srow = lane >> 3;
    const int skq  = (lane & 7) ^ ((lane >> 3) & 7);
    const unsigned short* aP0 =
        A + (size_t)(m0 + 16 * w + srow) * lda + skq * 8;
    const unsigned short* aP1 = aP0 + 8 * lda;
    const unsigned short* bP0 =
        Bt + (size_t)(n0b + 32 * w + srow) * ldb + skq * 8;
    const unsigned short* bP1 = bP0 + 8 * ldb;
    const unsigned short* bP2 = bP0 + 16 * ldb;
    const unsigned short* bP3 = bP0 + 24 * ldb;

    // ---- fragment geometry (wave-tile 64x64; 2M x 4N wave grid) ----
    const int wrow = (w >> 2) * 64;
    const int wcol = (w & 3) * 64;
    const int fr = lane & 15;
    const int fq = lane >> 4;          // 0..3
    const int swz0 = ((fq)     ^ (fr & 7)) * 8;   // swizzled k-offsets (shorts)
    const int swz1 = ((4 + fq) ^ (fr & 7)) * 8;

    f32x4 acc[4][4] = {};
    const int nt = K / TBK;            // 16 or 8

    auto STAGE = [&](int kt, int b) {
        const size_t ko = (size_t)kt * TBK;
        short* la = &sA[b][0];
        short* lb = &sB[b][0];
        GLL(aP0 + ko, la + (2 * w)     * 512);
        GLL(aP1 + ko, la + (2 * w + 1) * 512);
        GLL(bP0 + ko, lb + (4 * w)     * 512);
        GLL(bP1 + ko, lb + (4 * w + 1) * 512);
        GLL(bP2 + ko, lb + (4 * w + 2) * 512);
        GLL(bP3 + ko, lb + (4 * w + 3) * 512);
    };

    STAGE(0, 0);
    STAGE(1, 1);
    VMC(6);                            // tile 0 landed; tile 1 in flight
    BAR();
    SB0();

    int cur = 0, stg = 2;              // stg = (t+2)%3
    for (int t = 0; t < nt; ++t) {
        const short* sAp = &sA[cur][0];
        const short* sBp = &sB[cur][0];

        if (t + 2 < nt) STAGE(t + 2, stg);   // issue VMEM first (T3 ordering);
                                             // buffer freed at iter t-1
        bf16x8 af[2][4], bf[2][4];
        #pragma unroll
        for (int m = 0; m < 4; ++m) {
            const int r = (wrow + m * 16 + fr) * 64;
            af[0][m] = *reinterpret_cast<const bf16x8*>(&sAp[r + swz0]);
            af[1][m] = *reinterpret_cast<const bf16x8*>(&sAp[r + swz1]);
        }
        #pragma unroll
        for (int n = 0; n < 4; ++n) {
            const int r = (wcol + n * 16 + fr) * 64;
            bf[0][n] = *reinterpret_cast<const bf16x8*>(&sBp[r + swz0]);
            bf[1][n] = *reinterpret_cast<const bf16x8*>(&sBp[r + swz1]);
        }

        __builtin_amdgcn_s_setprio(1);
        #pragma unroll
        for (int kh = 0; kh < 2; ++kh)
            #pragma unroll
            for (int m = 0; m < 4; ++m)
                #pragma unroll
                for (int n = 0; n < 4; ++n)
                    acc[m][n] = __builtin_amdgcn_mfma_f32_16x16x32_bf16(
                        af[kh][m], bf[kh][n], acc[m][n], 0, 0, 0);
        __builtin_amdgcn_s_setprio(0);

        if (t + 1 < nt) {
            if (t + 2 < nt) { VMC(6); } else { VMC(0); }  // tile t+1 landed
            BAR();
            SB0();
        }
        cur = (cur == 2) ? 0 : cur + 1;
        stg = (stg == 2) ? 0 : stg + 1;
    }

    // C/D layout: col = lane&15, row = (lane>>4)*4 + reg  [m89/m91 verified]
    #pragma unroll
    for (int n = 0; n < 4; ++n) {
        const int cl = wcol + n * 16 + fr;
        const float bv = bias[n0b + cl];
        #pragma unroll
        for (int m = 0; m < 4; ++m) {
            const int rbase = m0 + wrow + m * 16 + fq * 4;
            #pragma unroll
            for (int r = 0; r < 4; ++r) {
                float v = fmaxf(acc[m][n][r] + bv, 0.0f);
                C[(size_t)(rbase + r) * ldc + c0 + cl] = f2bf(v);
            }
        }
    }
}

// XCD-bijective swizzle for 256-block grids (4 x 64): XCD k (= bid%8) gets
// sids 32k..32k+31 -> m-panels 8k..8k+7, all 4 n-tiles of each.
static __device__ __forceinline__ int xcd_sid() {
    const int bid = blockIdx.y * gridDim.x + blockIdx.x;   // 0..255
    return (bid & 7) * 32 + (bid >> 3);
}

__global__ __launch_bounds__(512, 2) void gemm_bf16(
    const unsigned short* __restrict__ A, int lda,
    const unsigned short* __restrict__ Bt, int ldb,
    const float* __restrict__ bias,
    unsigned short* __restrict__ C, int ldc, int K)
{
    const int sid = xcd_sid();
    const int n0 = (sid & 3) * TBN;
    const int m0 = (sid >> 2) * TBM;
    gemm_core(A, lda, Bt, ldb, bias, C, ldc, K, m0, n0, n0);
}

// Grouped L4: x' = sid&3 -> (g = x'>>1, n-half = x'&1)
__global__ __launch_bounds__(512, 2) void gemm_bf16_l4(
    const unsigned short* __restrict__ x3,
    const unsigned short* __restrict__ W41t,
    const unsigned short* __restrict__ W42t,
    const float* __restrict__ b41, const float* __restrict__ b42,
    unsigned short* __restrict__ x4)
{
    const int sid = xcd_sid();
    const int xp  = sid & 3;
    const int g   = xp >> 1;
    const int n0b = (xp & 1) * TBN;
    const int m0  = (sid >> 2) * TBM;
    const unsigned short* A  = x3 + (g ? 512 : 0);
    const unsigned short* Bt = g ? W42t : W41t;
    const float* bias        = g ? b42 : b41;
    gemm_core(A, 1024, Bt, 512, bias, x4, 1024, 512, m0, n0b, g * 512 + n0b);
}

// All prep in one kernel.
// z: 0=W2, 1=W31, 2=W32, 3=W41, 4=W42, 5=b3cat, 6=layer1 (x@W1+b1,relu->bf16)
__global__ __launch_bounds__(256) void prep_weights(
    const float* __restrict__ W2,  const float* __restrict__ W31,
    const float* __restrict__ W32, const float* __restrict__ W41,
    const float* __restrict__ W42, const float* __restrict__ b31,
    const float* __restrict__ b32,
    const float* __restrict__ x,   const float* __restrict__ W1,
    const float* __restrict__ b1,
    unsigned short* __restrict__ W2t,  unsigned short* __restrict__ W3t,
    unsigned short* __restrict__ W41t, unsigned short* __restrict__ W42t,
    float* __restrict__ b3c, unsigned short* __restrict__ xb1)
{
    const int z = blockIdx.z;
    if (z == 6) {
        // layer1: 32x32=1024 blocks, each does 8 rows x 1024 cols.
        const int r0 = (blockIdx.y * 32 + blockIdx.x) * 8;
        const int j4 = threadIdx.x * 4;
        float4 wv[5];
        #pragma unroll
        for (int k = 0; k < 5; ++k)
            wv[k] = *reinterpret_cast<const float4*>(&W1[k * 1024 + j4]);
        const float4 bb = *reinterpret_cast<const float4*>(&b1[j4]);
        #pragma unroll
        for (int r = 0; r < 8; ++r) {
            const float* xr = &x[(size_t)(r0 + r) * 5];
            float4 acc = bb;
            #pragma unroll
            for (int k = 0; k < 5; ++k) {
                const float xv = xr[k];
                acc.x = fmaf(xv, wv[k].x, acc.x);
                acc.y = fmaf(xv, wv[k].y, acc.y);
                acc.z = fmaf(xv, wv[k].z, acc.z);
                acc.w = fmaf(xv, wv[k].w, acc.w);
            }
            ushort4 o;
            o.x = f2bf(fmaxf(acc.x, 0.f));
            o.y = f2bf(fmaxf(acc.y, 0.f));
            o.z = f2bf(fmaxf(acc.z, 0.f));
            o.w = f2bf(fmaxf(acc.w, 0.f));
            *reinterpret_cast<ushort4*>(&xb1[(size_t)(r0 + r) * 1024 + j4]) = o;
        }
        return;
    }
    if (z == 5) {
        if (blockIdx.x == 0 && blockIdx.y == 0) {
            for (int i = threadIdx.x; i < 1024; i += 256)
                b3c[i] = (i < 512) ? b31[i] : b32[i - 512];
        }
        return;
    }
    const float* src; unsigned short* dst; int K, N;
    switch (z) {
        case 0:  src = W2;  dst = W2t;              K = 1024; N = 1024; break;
        case 1:  src = W31; dst = W3t;              K = 1024; N = 512;  break;
        case 2:  src = W32; dst = W3t + 512 * 1024; K = 1024; N = 512;  break;
        case 3:  src = W41; dst = W41t;             K = 512;  N = 512;  break;
        default: src = W42; dst = W42t;             K = 512;  N = 512;  break;
    }
    const int k0 = blockIdx.x * 32, n0 = blockIdx.y * 32;
    if (k0 >= K || n0 >= N) return;

    __shared__ float t[32][33];
    const int tx = threadIdx.x & 31, ty = threadIdx.x >> 5;  // 32 x 8
    #pragma unroll
    for (int i = 0; i < 32; i += 8)
        t[ty + i][tx] = src[(size_t)(k0 + ty + i) * N + n0 + tx];
    __syncthreads();
    #pragma unroll
    for (int i = 0; i < 32; i += 8)
        dst[(size_t)(n0 + ty + i) * K + k0 + tx] = f2bf(t[tx][ty + i]);
}

// Heads + exact CBF/QP epilogue. One wave per batch row; vectorized loads.
// Row map XCD-aligned to L4's swizzle: block b -> rows (b&7)*1024 + (b>>3)*4,
// so each block reads x4 rows resident in its own XCD's L2.
__global__ __launch_bounds__(256) void head_kernel(
    const unsigned short* __restrict__ x4,
    const float* __restrict__ W51, const float* __restrict__ b51,
    const float* __restrict__ W52, const float* __restrict__ b52,
    const float* __restrict__ x,   const float* __restrict__ mean,
    const float* __restrict__ stdv, const float* __restrict__ mean_label,
    const float* __restrict__ std_label, float* __restrict__ out)
{
    const int wave = threadIdx.x >> 6;
    const int lane = threadIdx.x & 63;
    const int bid = blockIdx.x;                      // 0..2047
    const int row = (bid & 7) * 1024 + (bid >> 3) * 4 + wave;

    const unsigned short* p41 = x4 + (size_t)row * 1024;
    const bf16x8 v1 = *reinterpret_cast<const bf16x8*>(p41 + lane * 8);
    const bf16x8 v2 = *reinterpret_cast<const bf16x8*>(p41 + 512 + lane * 8);
    const float4 q0 = *reinterpret_cast<const float4*>(W51 + lane * 16 + 0);
    const float4 q1 = *reinterpret_cast<const float4*>(W51 + lane * 16 + 4);
    const float4 q2 = *reinterpret_cast<const float4*>(W51 + lane * 16 + 8);
    const float4 q3 = *reinterpret_cast<const float4*>(W51 + lane * 16 + 12);
    const float4 s0 = *reinterpret_cast<const float4*>(W52 + lane * 16 + 0);
    const float4 s1 = *reinterpret_cast<const float4*>(W52 + lane * 16 + 4);
    const float4 s2 = *reinterpret_cast<const float4*>(W52 + lane * 16 + 8);
    const float4 s3 = *reinterpret_cast<const float4*>(W52 + lane * 16 + 12);

    float a0, a1, a2, a3;
    {
        const float e0 = bf2f((unsigned short)v1[0]), e1 = bf2f((unsigned short)v1[1]),
                    e2 = bf2f((unsigned short)v1[2]), e3 = bf2f((unsigned short)v1[3]),
                    e4 = bf2f((unsigned short)v1[4]), e5 = bf2f((unsigned short)v1[5]),
                    e6 = bf2f((unsigned short)v1[6]), e7 = bf2f((unsigned short)v1[7]);
        a0 = e0*q0.x + e1*q0.z + e2*q1.x + e3*q1.z + e4*q2.x + e5*q2.z + e6*q3.x + e7*q3.z;
        a1 = e0*q0.y + e1*q0.w + e2*q1.y + e3*q1.w + e4*q2.y + e5*q2.w + e6*q3.y + e7*q3.w;
        const float f0 = bf2f((unsigned short)v2[0]), f1 = bf2f((unsigned short)v2[1]),
                    f2 = bf2f((unsigned short)v2[2]), f3 = bf2f((unsigned short)v2[3]),
                    f4 = bf2f((unsigned short)v2[4]), f5 = bf2f((unsigned short)v2[5]),
                    f6 = bf2f((unsigned short)v2[6]), f7 = bf2f((unsigned short)v2[7]);
        a2 = f0*s0.x + f1*s0.z + f2*s1.x + f3*s1.z + f4*s2.x + f5*s2.z + f6*s3.x + f7*s3.z;
        a3 = f0*s0.y + f1*s0.w + f2*s1.y + f3*s1.w + f4*s2.y + f5*s2.w + f6*s3.y + f7*s3.w;
    }
    #pragma unroll
    for (int off = 32; off >= 1; off >>= 1) {
        a0 += __shfl_down(a0, off);
        a1 += __shfl_down(a1, off);
        a2 += __shfl_down(a2, off);
        a3 += __shfl_down(a3, off);
    }

    if (lane == 0) {
        const float L1c = 3.0f, L2c = 3.0f, OBSY = 7.0f, Rc = 4.0f;
        const float t1 = x[row * 5 + 0] * stdv[0] + mean[0];
        const float w1 = x[row * 5 + 1] * stdv[1] + mean[1];
        const float t2 = x[row * 5 + 2] * stdv[2] + mean[2];
        const float w2 = x[row * 5 + 3] * stdv[3] + mean[3];
        const float s1v = sinf(t1), c1 = cosf(t1);
        const float s2v = sinf(t2), c2 = cosf(t2);
        const float px = L1c * c1 + L2c * c2;
        const float py = L1c * s1v + L2c * s2v - OBSY;
        const float vx = -L1c * s1v * w1 - L2c * s2v * w2;
        const float vy =  L1c * c1 * w1 + L2c * c2 * w2;
        const float barrier = px * px + py * py - Rc * Rc;
        const float b_dot = 2.0f * (px * vx + py * vy);
        const float Lf2b = 2.0f * (vx * vx + vy * vy)
                         + 2.0f * px * (-L1c * c1 * w1 * w1 - L2c * c2 * w2 * w2)
                         + 2.0f * py * (-L1c * s1v * w1 * w1 - L2c * s2v * w2 * w2);
        const float G1 = -(2.0f * px * (-L1c * s1v) + 2.0f * py * (L1c * c1));
        const float G2 = -(2.0f * px * (-L2c * s2v) + 2.0f * py * (L2c * c2));

        const float x51_0 = a0 + b51[0];
        const float x51_1 = a1 + b51[1];
        const float z0 = a2 + b52[0];
        const float z1 = a3 + b52[1];
        const float x52_0 = 4.0f / (1.0f + expf(-z0));
        const float x52_1 = 4.0f / (1.0f + expf(-z1));

        const float u0_0 = -x51_0;
        const float u0_1 = -x51_1;
        const float h = Lf2b + (x52_0 + x52_1) * b_dot + x52_0 * x52_1 * barrier;
        const float viol = G1 * u0_0 + G2 * u0_1 - h;
        const float lam = fmaxf(viol, 0.0f) / (G1 * G1 + G2 * G2 + 1e-12f);
        const float u_0 = u0_0 - lam * G1;
        const float u_1 = u0_1 - lam * G2;
        out[row * 2 + 0] = (u_0 - mean_label[0]) / std_label[0];
        out[row * 2 + 1] = (u_1 - mean_label[1]) / std_label[1];
    }
}

extern "C" void kernel_launch(void* const* d_in, const int* in_sizes, int n_in,
                              void* d_out, int out_size, void* d_ws, size_t ws_size,
                              hipStream_t stream) {
    const float* x          = (const float*)d_in[0];
    const float* mean       = (const float*)d_in[2];
    const float* stdv       = (const float*)d_in[3];
    const float* mean_label = (const float*)d_in[4];
    const float* std_label  = (const float*)d_in[5];
    const float* W1  = (const float*)d_in[6];   const float* b1  = (const float*)d_in[7];
    const float* W2  = (const float*)d_in[8];   const float* b2  = (const float*)d_in[9];
    const float* W31 = (const float*)d_in[10];  const float* b31 = (const float*)d_in[11];
    const float* W32 = (const float*)d_in[12];  const float* b32 = (const float*)d_in[13];
    const float* W41 = (const float*)d_in[14];  const float* b41 = (const float*)d_in[15];
    const float* W42 = (const float*)d_in[16];  const float* b42 = (const float*)d_in[17];
    const float* W51 = (const float*)d_in[18];  const float* b51 = (const float*)d_in[19];
    const float* W52 = (const float*)d_in[20];  const float* b52 = (const float*)d_in[21];
    float* out = (float*)d_out;

    char* ws = (char*)d_ws;
    const size_t MiB = 1024 * 1024;
    unsigned short* xb1  = (unsigned short*)(ws + 0);         // later x3
    unsigned short* x2b  = (unsigned short*)(ws + 16 * MiB);  // later x4
    unsigned short* x3   = xb1;
    unsigned short* x4   = x2b;
    unsigned short* W2t  = (unsigned short*)(ws + 32 * MiB);
    unsigned short* W3t  = (unsigned short*)(ws + 34 * MiB);
    unsigned short* W41t = (unsigned short*)(ws + 36 * MiB);
    unsigned short* W42t = (unsigned short*)(ws + 36 * MiB + 512 * 1024);
    float*          b3c  = (float*)(ws + 37 * MiB);

    prep_weights<<<dim3(32, 32, 7), 256, 0, stream>>>(
        W2, W31, W32, W41, W42, b31, b32, x, W1, b1,
        W2t, W3t, W41t, W42t, b3c, xb1);

    dim3 gBig(1024 / TBN, 8192 / TBM);          // 4 x 64 = 256 blocks
    gemm_bf16<<<gBig, 512, 0, stream>>>(xb1, 1024, W2t, 1024, b2, x2b, 1024, 1024);
    gemm_bf16<<<gBig, 512, 0, stream>>>(x2b, 1024, W3t, 1024, b3c, x3, 1024, 1024);

    gemm_bf16_l4<<<dim3(4, 64), 512, 0, stream>>>(x3, W41t, W42t, b41, b42, x4);

    head_kernel<<<2048, 256, 0, stream>>>(x4, W51, b51, W52, b52,
                                          x, mean, stdv, mean_label, std_label, out);
}

// Round 12
// 79.083 us; speedup vs baseline: 2.7337x; 1.1097x over previous
//
#include <hip/hip_runtime.h>
#include <hip/hip_bf16.h>
#include <math.h>

// ---------------------------------------------------------------------------
// BarrierNet forward — FINAL = round 5 configuration verbatim (78.8us, best).
// GEMM: BM=128 x BN=256 x BK=64, 512 threads (8 waves, wave-tile 64x64),
// TRIPLE-buffered LDS (144 KiB), ONE barrier per K-tile, stage-ahead-2,
// counted s_waitcnt vmcnt(6) (never 0 mid-loop), s_setprio around MFMA.
// Conflict-free XOR-swizzled LDS via pre-swizzled GLOBAL source of
// global_load_lds (linear LDS dest) + same XOR on ds_read side.
// XCD swizzle: 256 blocks -> XCD k owns m-panels 8k..8k+7.
// Refuted variants (all slower): 8-phase fine interleave (R6: 90.9),
// 2-phase/16-MFMA (R8: 83.4), A-operand global->VGPR (R7: 134.8, 64 cache
// lines/instr), fat 64x128 waves (R9: 84.5, 1 wave/SIMD), cooperative
// mega-kernel (R10: 216, 650 GB/s + 8% MfmaUtil), STAGE-first reorder +
// head XCD remap (R11: 87.8).
// ---------------------------------------------------------------------------

typedef __attribute__((ext_vector_type(4))) float f32x4;
typedef __attribute__((ext_vector_type(8))) short bf16x8;

static __device__ __forceinline__ unsigned short f2bf(float f) {
    unsigned int u = __float_as_uint(f);
    unsigned int r = (u + 0x7fffu + ((u >> 16) & 1u)) >> 16;
    return (unsigned short)r;
}
static __device__ __forceinline__ float bf2f(unsigned short h) {
    return __uint_as_float(((unsigned int)h) << 16);
}

#define TBM 128
#define TBN 256
#define TBK 64

#define GLL(gp, lp) __builtin_amdgcn_global_load_lds( \
    (const __attribute__((address_space(1))) void*)(gp), \
    (__attribute__((address_space(3))) void*)(lp), 16, 0, 0)

#define VMC(N)  asm volatile("s_waitcnt vmcnt(" #N ")" ::: "memory")
#define BAR()   __builtin_amdgcn_s_barrier()
#define SB0()   __builtin_amdgcn_sched_barrier(0)

// C[., c0+j] = relu(A[m0+i,:] . Bt[n0b+j,:] + bias[n0b+j])
// A: bf16 row-major lda; Bt: bf16 row-major ldb (N x K); nt = K/64 >= 3.
__device__ __forceinline__ void gemm_core(
    const unsigned short* __restrict__ A, int lda,
    const unsigned short* __restrict__ Bt, int ldb,
    const float* __restrict__ bias,
    unsigned short* __restrict__ C, int ldc,
    int K, int m0, int n0b, int c0)
{
    // A tile 16 KiB, B tile 32 KiB, x3 buffers = 144 KiB
    __shared__ __align__(16) short sA[3][TBM * TBK];
    __shared__ __align__(16) short sB[3][TBN * TBK];

    const int tid  = threadIdx.x;
    const int w    = tid >> 6;         // wave 0..7
    const int lane = tid & 63;

    // ---- staging addresses (pre-swizzled global source) ----
    // chunk = 1 KiB = 64 granules = 8 rows x 8 granules. lane l covers
    // LDS granule chunkbase + l -> logical row = base + (l>>3),
    //                              kq = (l&7) ^ ((l>>3)&7)
    const int srow = lane >> 3;                       // 0..7
    const int skq  = (lane & 7) ^ ((lane >> 3) & 7);  // 0..7
    const unsigned short* aP0 =
        A + (size_t)(m0 + 16 * w + srow) * lda + skq * 8;
    const unsigned short* aP1 = aP0 + 8 * lda;
    const unsigned short* bP0 =
        Bt + (size_t)(n0b + 32 * w + srow) * ldb + skq * 8;
    const unsigned short* bP1 = bP0 + 8 * ldb;
    const unsigned short* bP2 = bP0 + 16 * ldb;
    const unsigned short* bP3 = bP0 + 24 * ldb;

    // ---- fragment geometry (wave-tile 64x64; 2M x 4N wave grid) ----
    const int wrow = (w >> 2) * 64;
    const int wcol = (w & 3) * 64;
    const int fr = lane & 15;
    const int fq = lane >> 4;          // 0..3
    const int swz0 = ((fq)     ^ (fr & 7)) * 8;   // swizzled k-offsets (shorts)
    const int swz1 = ((4 + fq) ^ (fr & 7)) * 8;

    f32x4 acc[4][4] = {};
    const int nt = K / TBK;            // 16 or 8

    auto STAGE = [&](int kt, int b) {
        const size_t ko = (size_t)kt * TBK;
        short* la = &sA[b][0];
        short* lb = &sB[b][0];
        GLL(aP0 + ko, la + (2 * w)     * 512);
        GLL(aP1 + ko, la + (2 * w + 1) * 512);
        GLL(bP0 + ko, lb + (4 * w)     * 512);
        GLL(bP1 + ko, lb + (4 * w + 1) * 512);
        GLL(bP2 + ko, lb + (4 * w + 2) * 512);
        GLL(bP3 + ko, lb + (4 * w + 3) * 512);
    };

    STAGE(0, 0);
    STAGE(1, 1);
    VMC(6);                            // tile 0 landed; tile 1 in flight
    BAR();
    SB0();

    int cur = 0, stg = 2;              // stg = (t+2)%3
    for (int t = 0; t < nt; ++t) {
        const short* sAp = &sA[cur][0];
        const short* sBp = &sB[cur][0];

        bf16x8 af[2][4], bf[2][4];
        #pragma unroll
        for (int m = 0; m < 4; ++m) {
            const int r = (wrow + m * 16 + fr) * 64;
            af[0][m] = *reinterpret_cast<const bf16x8*>(&sAp[r + swz0]);
            af[1][m] = *reinterpret_cast<const bf16x8*>(&sAp[r + swz1]);
        }
        #pragma unroll
        for (int n = 0; n < 4; ++n) {
            const int r = (wcol + n * 16 + fr) * 64;
            bf[0][n] = *reinterpret_cast<const bf16x8*>(&sBp[r + swz0]);
            bf[1][n] = *reinterpret_cast<const bf16x8*>(&sBp[r + swz1]);
        }

        if (t + 2 < nt) STAGE(t + 2, stg);   // buffer freed at iter t-1

        __builtin_amdgcn_s_setprio(1);
        #pragma unroll
        for (int kh = 0; kh < 2; ++kh)
            #pragma unroll
            for (int m = 0; m < 4; ++m)
                #pragma unroll
                for (int n = 0; n < 4; ++n)
                    acc[m][n] = __builtin_amdgcn_mfma_f32_16x16x32_bf16(
                        af[kh][m], bf[kh][n], acc[m][n], 0, 0, 0);
        __builtin_amdgcn_s_setprio(0);

        if (t + 1 < nt) {
            if (t + 2 < nt) { VMC(6); } else { VMC(0); }  // tile t+1 landed
            BAR();
            SB0();
        }
        cur = (cur == 2) ? 0 : cur + 1;
        stg = (stg == 2) ? 0 : stg + 1;
    }

    // C/D layout: col = lane&15, row = (lane>>4)*4 + reg  [m89/m91 verified]
    #pragma unroll
    for (int n = 0; n < 4; ++n) {
        const int cl = wcol + n * 16 + fr;
        const float bv = bias[n0b + cl];
        #pragma unroll
        for (int m = 0; m < 4; ++m) {
            const int rbase = m0 + wrow + m * 16 + fq * 4;
            #pragma unroll
            for (int r = 0; r < 4; ++r) {
                float v = fmaxf(acc[m][n][r] + bv, 0.0f);
                C[(size_t)(rbase + r) * ldc + c0 + cl] = f2bf(v);
            }
        }
    }
}

// XCD-bijective swizzle for 256-block grids (4 x 64): XCD k (= bid%8) gets
// sids 32k..32k+31 -> m-panels 8k..8k+7, all 4 n-tiles of each.
static __device__ __forceinline__ int xcd_sid() {
    const int bid = blockIdx.y * gridDim.x + blockIdx.x;   // 0..255
    return (bid & 7) * 32 + (bid >> 3);
}

__global__ __launch_bounds__(512, 2) void gemm_bf16(
    const unsigned short* __restrict__ A, int lda,
    const unsigned short* __restrict__ Bt, int ldb,
    const float* __restrict__ bias,
    unsigned short* __restrict__ C, int ldc, int K)
{
    const int sid = xcd_sid();
    const int n0 = (sid & 3) * TBN;
    const int m0 = (sid >> 2) * TBM;
    gemm_core(A, lda, Bt, ldb, bias, C, ldc, K, m0, n0, n0);
}

// Grouped L4: x' = sid&3 -> (g = x'>>1, n-half = x'&1)
__global__ __launch_bounds__(512, 2) void gemm_bf16_l4(
    const unsigned short* __restrict__ x3,
    const unsigned short* __restrict__ W41t,
    const unsigned short* __restrict__ W42t,
    const float* __restrict__ b41, const float* __restrict__ b42,
    unsigned short* __restrict__ x4)
{
    const int sid = xcd_sid();
    const int xp  = sid & 3;
    const int g   = xp >> 1;
    const int n0b = (xp & 1) * TBN;
    const int m0  = (sid >> 2) * TBM;
    const unsigned short* A  = x3 + (g ? 512 : 0);
    const unsigned short* Bt = g ? W42t : W41t;
    const float* bias        = g ? b42 : b41;
    gemm_core(A, 1024, Bt, 512, bias, x4, 1024, 512, m0, n0b, g * 512 + n0b);
}

// All prep in one kernel.
// z: 0=W2, 1=W31, 2=W32, 3=W41, 4=W42, 5=b3cat, 6=layer1 (x@W1+b1,relu->bf16)
__global__ __launch_bounds__(256) void prep_weights(
    const float* __restrict__ W2,  const float* __restrict__ W31,
    const float* __restrict__ W32, const float* __restrict__ W41,
    const float* __restrict__ W42, const float* __restrict__ b31,
    const float* __restrict__ b32,
    const float* __restrict__ x,   const float* __restrict__ W1,
    const float* __restrict__ b1,
    unsigned short* __restrict__ W2t,  unsigned short* __restrict__ W3t,
    unsigned short* __restrict__ W41t, unsigned short* __restrict__ W42t,
    float* __restrict__ b3c, unsigned short* __restrict__ xb1)
{
    const int z = blockIdx.z;
    if (z == 6) {
        // layer1: 32x32=1024 blocks, each does 8 rows x 1024 cols.
        const int r0 = (blockIdx.y * 32 + blockIdx.x) * 8;
        const int j4 = threadIdx.x * 4;
        float4 wv[5];
        #pragma unroll
        for (int k = 0; k < 5; ++k)
            wv[k] = *reinterpret_cast<const float4*>(&W1[k * 1024 + j4]);
        const float4 bb = *reinterpret_cast<const float4*>(&b1[j4]);
        #pragma unroll
        for (int r = 0; r < 8; ++r) {
            const float* xr = &x[(size_t)(r0 + r) * 5];
            float4 acc = bb;
            #pragma unroll
            for (int k = 0; k < 5; ++k) {
                const float xv = xr[k];
                acc.x = fmaf(xv, wv[k].x, acc.x);
                acc.y = fmaf(xv, wv[k].y, acc.y);
                acc.z = fmaf(xv, wv[k].z, acc.z);
                acc.w = fmaf(xv, wv[k].w, acc.w);
            }
            ushort4 o;
            o.x = f2bf(fmaxf(acc.x, 0.f));
            o.y = f2bf(fmaxf(acc.y, 0.f));
            o.z = f2bf(fmaxf(acc.z, 0.f));
            o.w = f2bf(fmaxf(acc.w, 0.f));
            *reinterpret_cast<ushort4*>(&xb1[(size_t)(r0 + r) * 1024 + j4]) = o;
        }
        return;
    }
    if (z == 5) {
        if (blockIdx.x == 0 && blockIdx.y == 0) {
            for (int i = threadIdx.x; i < 1024; i += 256)
                b3c[i] = (i < 512) ? b31[i] : b32[i - 512];
        }
        return;
    }
    const float* src; unsigned short* dst; int K, N;
    switch (z) {
        case 0:  src = W2;  dst = W2t;              K = 1024; N = 1024; break;
        case 1:  src = W31; dst = W3t;              K = 1024; N = 512;  break;
        case 2:  src = W32; dst = W3t + 512 * 1024; K = 1024; N = 512;  break;
        case 3:  src = W41; dst = W41t;             K = 512;  N = 512;  break;
        default: src = W42; dst = W42t;             K = 512;  N = 512;  break;
    }
    const int k0 = blockIdx.x * 32, n0 = blockIdx.y * 32;
    if (k0 >= K || n0 >= N) return;

    __shared__ float t[32][33];
    const int tx = threadIdx.x & 31, ty = threadIdx.x >> 5;  // 32 x 8
    #pragma unroll
    for (int i = 0; i < 32; i += 8)
        t[ty + i][tx] = src[(size_t)(k0 + ty + i) * N + n0 + tx];
    __syncthreads();
    #pragma unroll
    for (int i = 0; i < 32; i += 8)
        dst[(size_t)(n0 + ty + i) * K + k0 + tx] = f2bf(t[tx][ty + i]);
}

// Heads + exact CBF/QP epilogue. One wave per batch row; vectorized loads.
// lane covers k = lane*8 .. lane*8+7 of each 512-dot.
__global__ __launch_bounds__(256) void head_kernel(
    const unsigned short* __restrict__ x4,
    const float* __restrict__ W51, const float* __restrict__ b51,
    const float* __restrict__ W52, const float* __restrict__ b52,
    const float* __restrict__ x,   const float* __restrict__ mean,
    const float* __restrict__ stdv, const float* __restrict__ mean_label,
    const float* __restrict__ std_label, float* __restrict__ out)
{
    const int wave = threadIdx.x >> 6;
    const int lane = threadIdx.x & 63;
    const int row = blockIdx.x * 4 + wave;

    const unsigned short* p41 = x4 + (size_t)row * 1024;
    const bf16x8 v1 = *reinterpret_cast<const bf16x8*>(p41 + lane * 8);
    const bf16x8 v2 = *reinterpret_cast<const bf16x8*>(p41 + 512 + lane * 8);
    // W5x[k*2 .. k*2+1] for k in [lane*8, lane*8+8) = 16 contiguous floats
    const float4 q0 = *reinterpret_cast<const float4*>(W51 + lane * 16 + 0);
    const float4 q1 = *reinterpret_cast<const float4*>(W51 + lane * 16 + 4);
    const float4 q2 = *reinterpret_cast<const float4*>(W51 + lane * 16 + 8);
    const float4 q3 = *reinterpret_cast<const float4*>(W51 + lane * 16 + 12);
    const float4 s0 = *reinterpret_cast<const float4*>(W52 + lane * 16 + 0);
    const float4 s1 = *reinterpret_cast<const float4*>(W52 + lane * 16 + 4);
    const float4 s2 = *reinterpret_cast<const float4*>(W52 + lane * 16 + 8);
    const float4 s3 = *reinterpret_cast<const float4*>(W52 + lane * 16 + 12);

    float a0, a1, a2, a3;
    {
        const float e0 = bf2f((unsigned short)v1[0]), e1 = bf2f((unsigned short)v1[1]),
                    e2 = bf2f((unsigned short)v1[2]), e3 = bf2f((unsigned short)v1[3]),
                    e4 = bf2f((unsigned short)v1[4]), e5 = bf2f((unsigned short)v1[5]),
                    e6 = bf2f((unsigned short)v1[6]), e7 = bf2f((unsigned short)v1[7]);
        a0 = e0*q0.x + e1*q0.z + e2*q1.x + e3*q1.z + e4*q2.x + e5*q2.z + e6*q3.x + e7*q3.z;
        a1 = e0*q0.y + e1*q0.w + e2*q1.y + e3*q1.w + e4*q2.y + e5*q2.w + e6*q3.y + e7*q3.w;
        const float f0 = bf2f((unsigned short)v2[0]), f1 = bf2f((unsigned short)v2[1]),
                    f2 = bf2f((unsigned short)v2[2]), f3 = bf2f((unsigned short)v2[3]),
                    f4 = bf2f((unsigned short)v2[4]), f5 = bf2f((unsigned short)v2[5]),
                    f6 = bf2f((unsigned short)v2[6]), f7 = bf2f((unsigned short)v2[7]);
        a2 = f0*s0.x + f1*s0.z + f2*s1.x + f3*s1.z + f4*s2.x + f5*s2.z + f6*s3.x + f7*s3.z;
        a3 = f0*s0.y + f1*s0.w + f2*s1.y + f3*s1.w + f4*s2.y + f5*s2.w + f6*s3.y + f7*s3.w;
    }
    #pragma unroll
    for (int off = 32; off >= 1; off >>= 1) {
        a0 += __shfl_down(a0, off);
        a1 += __shfl_down(a1, off);
        a2 += __shfl_down(a2, off);
        a3 += __shfl_down(a3, off);
    }

    if (lane == 0) {
        const float L1c = 3.0f, L2c = 3.0f, OBSX = 0.0f, OBSY = 7.0f, Rc = 4.0f;
        const float t1 = x[row * 5 + 0] * stdv[0] + mean[0];
        const float w1 = x[row * 5 + 1] * stdv[1] + mean[1];
        const float t2 = x[row * 5 + 2] * stdv[2] + mean[2];
        const float w2 = x[row * 5 + 3] * stdv[3] + mean[3];
        const float s1v = sinf(t1), c1 = cosf(t1);
        const float s2v = sinf(t2), c2 = cosf(t2);
        const float px = L1c * c1 + L2c * c2 - OBSX;
        const float py = L1c * s1v + L2c * s2v - OBSY;
        const float vx = -L1c * s1v * w1 - L2c * s2v * w2;
        const float vy =  L1c * c1 * w1 + L2c * c2 * w2;
        const float barrier = px * px + py * py - Rc * Rc;
        const float b_dot = 2.0f * (px * vx + py * vy);
        const float Lf2b = 2.0f * (vx * vx + vy * vy)
                         + 2.0f * px * (-L1c * c1 * w1 * w1 - L2c * c2 * w2 * w2)
                         + 2.0f * py * (-L1c * s1v * w1 * w1 - L2c * s2v * w2 * w2);
        const float G1 = -(2.0f * px * (-L1c * s1v) + 2.0f * py * (L1c * c1));
        const float G2 = -(2.0f * px * (-L2c * s2v) + 2.0f * py * (L2c * c2));

        const float x51_0 = a0 + b51[0];
        const float x51_1 = a1 + b51[1];
        const float z0 = a2 + b52[0];
        const float z1 = a3 + b52[1];
        const float x52_0 = 4.0f / (1.0f + expf(-z0));
        const float x52_1 = 4.0f / (1.0f + expf(-z1));

        const float u0_0 = -x51_0;
        const float u0_1 = -x51_1;
        const float h = Lf2b + (x52_0 + x52_1) * b_dot + x52_0 * x52_1 * barrier;
        const float viol = G1 * u0_0 + G2 * u0_1 - h;
        const float lam = fmaxf(viol, 0.0f) / (G1 * G1 + G2 * G2 + 1e-12f);
        const float u_0 = u0_0 - lam * G1;
        const float u_1 = u0_1 - lam * G2;
        out[row * 2 + 0] = (u_0 - mean_label[0]) / std_label[0];
        out[row * 2 + 1] = (u_1 - mean_label[1]) / std_label[1];
    }
}

extern "C" void kernel_launch(void* const* d_in, const int* in_sizes, int n_in,
                              void* d_out, int out_size, void* d_ws, size_t ws_size,
                              hipStream_t stream) {
    const float* x          = (const float*)d_in[0];
    const float* mean       = (const float*)d_in[2];
    const float* stdv       = (const float*)d_in[3];
    const float* mean_label = (const float*)d_in[4];
    const float* std_label  = (const float*)d_in[5];
    const float* W1  = (const float*)d_in[6];   const float* b1  = (const float*)d_in[7];
    const float* W2  = (const float*)d_in[8];   const float* b2  = (const float*)d_in[9];
    const float* W31 = (const float*)d_in[10];  const float* b31 = (const float*)d_in[11];
    const float* W32 = (const float*)d_in[12];  const float* b32 = (const float*)d_in[13];
    const float* W41 = (const float*)d_in[14];  const float* b41 = (const float*)d_in[15];
    const float* W42 = (const float*)d_in[16];  const float* b42 = (const float*)d_in[17];
    const float* W51 = (const float*)d_in[18];  const float* b51 = (const float*)d_in[19];
    const float* W52 = (const float*)d_in[20];  const float* b52 = (const float*)d_in[21];
    float* out = (float*)d_out;

    char* ws = (char*)d_ws;
    const size_t MiB = 1024 * 1024;
    unsigned short* xb1  = (unsigned short*)(ws + 0);         // later x3
    unsigned short* x2b  = (unsigned short*)(ws + 16 * MiB);  // later x4
    unsigned short* x3   = xb1;
    unsigned short* x4   = x2b;
    unsigned short* W2t  = (unsigned short*)(ws + 32 * MiB);
    unsigned short* W3t  = (unsigned short*)(ws + 34 * MiB);
    unsigned short* W41t = (unsigned short*)(ws + 36 * MiB);
    unsigned short* W42t = (unsigned short*)(ws + 36 * MiB + 512 * 1024);
    float*          b3c  = (float*)(ws + 37 * MiB);

    prep_weights<<<dim3(32, 32, 7), 256, 0, stream>>>(
        W2, W31, W32, W41, W42, b31, b32, x, W1, b1,
        W2t, W3t, W41t, W42t, b3c, xb1);

    dim3 gBig(1024 / TBN, 8192 / TBM);          // 4 x 64 = 256 blocks
    gemm_bf16<<<gBig, 512, 0, stream>>>(xb1, 1024, W2t, 1024, b2, x2b, 1024, 1024);
    gemm_bf16<<<gBig, 512, 0, stream>>>(x2b, 1024, W3t, 1024, b3c, x3, 1024, 1024);

    gemm_bf16_l4<<<dim3(4, 64), 512, 0, stream>>>(x3, W41t, W42t, b41, b42, x4);

    head_kernel<<<2048, 256, 0, stream>>>(x4, W51, b51, W52, b52,
                                          x, mean, stdv, mean_label, std_label, out);
}